// Round 1
// baseline (789.818 us; speedup 1.0000x reference)
//
#include <hip/hip_runtime.h>
#include <cstddef>

#define NN 50000          // number of nodes
#define WPB 4             // waves per block in attn kernel
#define SCAN_B 256
#define NB1 ((NN + SCAN_B - 1) / SCAN_B)   // 196 scan blocks

// ---------------------------------------------------------------------------
// block-wide inclusive scan (blockDim.x = 256 = 4 waves)
// ---------------------------------------------------------------------------
__device__ __forceinline__ int block_inc_scan(int x, int* lds) {
    int lane = threadIdx.x & 63;
    int wid  = threadIdx.x >> 6;
#pragma unroll
    for (int d = 1; d < 64; d <<= 1) {
        int v = __shfl_up(x, d, 64);
        if (lane >= d) x += v;
    }
    if (lane == 63) lds[wid] = x;
    __syncthreads();
    if (wid == 0 && lane < 4) {
        int s = lds[lane];
#pragma unroll
        for (int d = 1; d < 4; d <<= 1) {
            int v = __shfl_up(s, d, 64);
            if (lane >= d) s += v;
        }
        lds[lane] = s;
    }
    __syncthreads();
    if (wid > 0) x += lds[wid - 1];
    return x;
}

// ---------------------------------------------------------------------------
// K2: fused histogram + per-edge rank (only atomic pass: 800K atomics)
// ---------------------------------------------------------------------------
__global__ void hist_rank_kernel(const int* __restrict__ dst, int* __restrict__ counts,
                                 int* __restrict__ rank, int E) {
    int i = blockIdx.x * blockDim.x + threadIdx.x;
    if (i < E) {
        int d = dst[i];
        rank[i] = atomicAdd(&counts[d], 1);
    }
}

// ---------------------------------------------------------------------------
// K3a: per-block sums of counts (coalesced)
// ---------------------------------------------------------------------------
__global__ __launch_bounds__(SCAN_B) void scan_sum_kernel(const int* __restrict__ counts,
                                                          int* __restrict__ bsum) {
    __shared__ int lds[4];
    int i = blockIdx.x * SCAN_B + threadIdx.x;
    int c = (i < NN) ? counts[i] : 0;
    int inc = block_inc_scan(c, lds);
    if (threadIdx.x == SCAN_B - 1) bsum[blockIdx.x] = inc;
}

// K3b: single block scans the 196 block sums -> exclusive bases; offsets[NN]=E
__global__ __launch_bounds__(SCAN_B) void scan_base_kernel(const int* __restrict__ bsum,
                                                           int* __restrict__ bbase,
                                                           int* __restrict__ offsets) {
    __shared__ int lds[4];
    int t = threadIdx.x;
    int c = (t < NB1) ? bsum[t] : 0;
    int inc = block_inc_scan(c, lds);
    if (t < NB1) bbase[t] = inc - c;             // exclusive base of block t
    if (t == NB1 - 1) offsets[NN] = inc;         // total = E
}

// K3c: final offsets (coalesced block scan + base)
__global__ __launch_bounds__(SCAN_B) void scan_off_kernel(const int* __restrict__ counts,
                                                          const int* __restrict__ bbase,
                                                          int* __restrict__ offsets) {
    __shared__ int lds[4];
    int i = blockIdx.x * SCAN_B + threadIdx.x;
    int c = (i < NN) ? counts[i] : 0;
    int inc = block_inc_scan(c, lds);
    if (i < NN) offsets[i] = bbase[blockIdx.x] + inc - c;   // exclusive scan
}

// ---------------------------------------------------------------------------
// K4: atomic-free placement into CSR order (stable)
// ---------------------------------------------------------------------------
__global__ void place_kernel(const int* __restrict__ dst, const int* __restrict__ rank,
                             const int* __restrict__ offsets, int* __restrict__ sorted, int E) {
    int i = blockIdx.x * blockDim.x + threadIdx.x;
    if (i < E) {
        int d = dst[i];
        sorted[offsets[d] + rank[i]] = i;
    }
}

// ---------------------------------------------------------------------------
// K5: one wave per node. lane = e_slot*8 + h  (8 edges x 8 heads per wave).
// Head h owns: deg0 channels 4h..4h+3 (1 x float4) and deg1 flat 12h..12h+11
// (3 x float4; 48h bytes is 16B aligned). Softmax without max subtraction
// (scores ~N(0,0.125); exp cannot overflow; softmax is shift-invariant).
//
// v2: (a) row edge-ids prefetched into one register/lane (deg<=64 path does
// ZERO per-iteration sorted loads — edge id comes from __shfl, removing one
// serial memory latency per group); (b) 2x8-edge unroll: all 16 float4 k/v
// loads issued before any FMA to double outstanding memory requests.
// ---------------------------------------------------------------------------
__global__ __launch_bounds__(256) void attn_kernel(
    const float* __restrict__ q0, const float* __restrict__ q1,
    const float* __restrict__ k0, const float* __restrict__ k1,
    const float* __restrict__ v0, const float* __restrict__ v1,
    const int* __restrict__ offsets, const int* __restrict__ sorted,
    float* __restrict__ out)
{
    int wave = threadIdx.x >> 6;
    int node = blockIdx.x * WPB + wave;
    if (node >= NN) return;
    int lane = threadIdx.x & 63;
    int h  = lane & 7;
    int es = lane >> 3;

    int rs = offsets[node], re = offsets[node + 1];
    int deg = re - rs;

    if (deg == 0) {               // no edges: output zeros (matches reference)
        if (es == 0) {
            float4 z; z.x = z.y = z.z = z.w = 0.f;
            *(float4*)(out + (size_t)node * 32 + 4 * h) = z;
            float* o1 = out + (size_t)NN * 32 + (size_t)node * 96 + 12 * h;
            ((float4*)o1)[0] = z; ((float4*)o1)[1] = z; ((float4*)o1)[2] = z;
        }
        return;
    }

    // Prefetch up to 64 edge ids of this row (clamped; deg<=64 covers ~all nodes)
    int si = sorted[rs + min(lane, deg - 1)];

    const float4 qa = *(const float4*)(q0 + (size_t)node * 32 + 4 * h);
    const float4* q1p = (const float4*)(q1 + (size_t)node * 96 + 12 * h);
    const float4 qb = q1p[0], qc = q1p[1], qd = q1p[2];

    float acc[16];
#pragma unroll
    for (int j = 0; j < 16; ++j) acc[j] = 0.f;
    float l = 0.f;

    const int nG = (deg + 7) >> 3;     // number of 8-edge groups

    for (int g = 0; g < nG; g += 2) {
        // ---- edge ids for both groups (no dependent load for g<8) ----
        int j0 = (g << 3) + es;
        int e0;
        if (g < 8) e0 = __shfl(si, j0, 64);
        else       e0 = sorted[rs + ((j0 < deg) ? j0 : 0)];
        bool ok0 = j0 < deg;

        int g1 = g + 1;
        int j1 = (g1 << 3) + es;
        int e1;
        if (g1 < 8) e1 = __shfl(si, j1 & 63, 64);
        else        e1 = sorted[rs + ((j1 < deg) ? j1 : 0)];
        bool ok1 = (g1 < nG) && (j1 < deg);

        // ---- issue ALL 16 float4 loads up front (max MLP) ----
        const float4 ka0 = *(const float4*)(k0 + (size_t)e0 * 32 + 4 * h);
        const float4* k1p0 = (const float4*)(k1 + (size_t)e0 * 96 + 12 * h);
        const float4 kb0 = k1p0[0], kc0 = k1p0[1], kd0 = k1p0[2];
        const float4 ua0 = *(const float4*)(v0 + (size_t)e0 * 32 + 4 * h);
        const float4* v1p0 = (const float4*)(v1 + (size_t)e0 * 96 + 12 * h);
        const float4 ub0 = v1p0[0], uc0 = v1p0[1], ud0 = v1p0[2];

        const float4 ka1 = *(const float4*)(k0 + (size_t)e1 * 32 + 4 * h);
        const float4* k1p1 = (const float4*)(k1 + (size_t)e1 * 96 + 12 * h);
        const float4 kb1 = k1p1[0], kc1 = k1p1[1], kd1 = k1p1[2];
        const float4 ua1 = *(const float4*)(v0 + (size_t)e1 * 32 + 4 * h);
        const float4* v1p1 = (const float4*)(v1 + (size_t)e1 * 96 + 12 * h);
        const float4 ub1 = v1p1[0], uc1 = v1p1[1], ud1 = v1p1[2];

        // ---- scores ----
        float s0 = qa.x * ka0.x + qa.y * ka0.y + qa.z * ka0.z + qa.w * ka0.w
                 + qb.x * kb0.x + qb.y * kb0.y + qb.z * kb0.z + qb.w * kb0.w
                 + qc.x * kc0.x + qc.y * kc0.y + qc.z * kc0.z + qc.w * kc0.w
                 + qd.x * kd0.x + qd.y * kd0.y + qd.z * kd0.z + qd.w * kd0.w;
        float s1 = qa.x * ka1.x + qa.y * ka1.y + qa.z * ka1.z + qa.w * ka1.w
                 + qb.x * kb1.x + qb.y * kb1.y + qb.z * kb1.z + qb.w * kb1.w
                 + qc.x * kc1.x + qc.y * kc1.y + qc.z * kc1.z + qc.w * kc1.w
                 + qd.x * kd1.x + qd.y * kd1.y + qd.z * kd1.z + qd.w * kd1.w;

        float w0 = ok0 ? __expf(s0 * 0.08838834764831845f) : 0.f; // 1/sqrt(128)
        float w1 = ok1 ? __expf(s1 * 0.08838834764831845f) : 0.f;
        l += w0 + w1;

        acc[0]  += w0 * ua0.x + w1 * ua1.x;
        acc[1]  += w0 * ua0.y + w1 * ua1.y;
        acc[2]  += w0 * ua0.z + w1 * ua1.z;
        acc[3]  += w0 * ua0.w + w1 * ua1.w;
        acc[4]  += w0 * ub0.x + w1 * ub1.x;
        acc[5]  += w0 * ub0.y + w1 * ub1.y;
        acc[6]  += w0 * ub0.z + w1 * ub1.z;
        acc[7]  += w0 * ub0.w + w1 * ub1.w;
        acc[8]  += w0 * uc0.x + w1 * uc1.x;
        acc[9]  += w0 * uc0.y + w1 * uc1.y;
        acc[10] += w0 * uc0.z + w1 * uc1.z;
        acc[11] += w0 * uc0.w + w1 * uc1.w;
        acc[12] += w0 * ud0.x + w1 * ud1.x;
        acc[13] += w0 * ud0.y + w1 * ud1.y;
        acc[14] += w0 * ud0.z + w1 * ud1.z;
        acc[15] += w0 * ud0.w + w1 * ud1.w;
    }

#pragma unroll
    for (int m = 8; m < 64; m <<= 1) {
        l += __shfl_xor(l, m, 64);
#pragma unroll
        for (int j = 0; j < 16; ++j) acc[j] += __shfl_xor(acc[j], m, 64);
    }

    if (es == 0) {
        float r = (l > 0.f) ? (1.0f / l) : 0.f;
        float4 o0; o0.x = acc[0] * r; o0.y = acc[1] * r; o0.z = acc[2] * r; o0.w = acc[3] * r;
        *(float4*)(out + (size_t)node * 32 + 4 * h) = o0;
        float* o1 = out + (size_t)NN * 32 + (size_t)node * 96 + 12 * h;
        float4 t0; t0.x = acc[4]  * r; t0.y = acc[5]  * r; t0.z = acc[6]  * r; t0.w = acc[7]  * r;
        float4 t1; t1.x = acc[8]  * r; t1.y = acc[9]  * r; t1.z = acc[10] * r; t1.w = acc[11] * r;
        float4 t2; t2.x = acc[12] * r; t2.y = acc[13] * r; t2.z = acc[14] * r; t2.w = acc[15] * r;
        ((float4*)o1)[0] = t0;
        ((float4*)o1)[1] = t1;
        ((float4*)o1)[2] = t2;
    }
}

// ---------------------------------------------------------------------------
extern "C" void kernel_launch(void* const* d_in, const int* in_sizes, int n_in,
                              void* d_out, int out_size, void* d_ws, size_t ws_size,
                              hipStream_t stream) {
    const float* q0 = (const float*)d_in[0];
    const float* q1 = (const float*)d_in[1];
    const float* k0 = (const float*)d_in[2];
    const float* k1 = (const float*)d_in[3];
    const float* v0 = (const float*)d_in[4];
    const float* v1 = (const float*)d_in[5];
    const int*  dst = (const int*)d_in[6];
    const int E = in_sizes[6];
    float* out = (float*)d_out;

    // ws layout (ints): offsets[NN+1] | counts[NN] | bsum[NB1] | bbase[NB1] | rank[E] | sorted[E]
    int* offsets = (int*)d_ws;
    int* counts  = offsets + (NN + 1);
    int* bsum    = counts + NN;
    int* bbase   = bsum + NB1;
    int* rank    = bbase + NB1;
    int* sorted  = rank + E;

    hipMemsetAsync(counts, 0, NN * sizeof(int), stream);
    hist_rank_kernel<<<(E + 255) / 256, 256, 0, stream>>>(dst, counts, rank, E);
    scan_sum_kernel<<<NB1, SCAN_B, 0, stream>>>(counts, bsum);
    scan_base_kernel<<<1, SCAN_B, 0, stream>>>(bsum, bbase, offsets);
    scan_off_kernel<<<NB1, SCAN_B, 0, stream>>>(counts, bbase, offsets);
    place_kernel<<<(E + 255) / 256, 256, 0, stream>>>(dst, rank, offsets, sorted, E);
    attn_kernel<<<(NN + WPB - 1) / WPB, 256, 0, stream>>>(
        q0, q1, k0, k1, v0, v1, offsets, sorted, out);
}